// Round 12
// baseline (686.592 us; speedup 1.0000x reference)
//
#include <hip/hip_runtime.h>
#include <hip/hip_cooperative_groups.h>
#include <math.h>

namespace cg = cooperative_groups;

#define N_NODES 100000
#define N_EDGES 1600000
#define D 128
#define NBKT 391   // ceil(N_NODES/256) buckets of 256 dst nodes

typedef __attribute__((ext_vector_type(8))) short short8;
typedef __attribute__((ext_vector_type(4))) float floatx4;

__device__ __forceinline__ float bf2f(unsigned short u) {
    union { unsigned int i; float f; } v;
    v.i = ((unsigned int)u) << 16;
    return v.f;
}
__device__ __forceinline__ unsigned short f2bf(float f) {
    union { float f; unsigned int i; } v;
    v.f = f;
    unsigned int u = v.i;
    u += 0x7fffu + ((u >> 16) & 1u);
    return (unsigned short)(u >> 16);
}
__device__ __forceinline__ unsigned short f2h(float f) {
    union { _Float16 h; unsigned short u; } c;
    c.h = (_Float16)f;
    return c.u;
}
__device__ __forceinline__ float h2f(unsigned short u) {
    union { unsigned short u; _Float16 h; } c;
    c.u = u;
    return (float)c.h;
}

// split 8 consecutive fp32 into hi/lo bf16 fragments (RNE) — in-register
__device__ __forceinline__ void split8(const float* __restrict__ p, short8& hi, short8& lo) {
    float4 v0 = *(const float4*)p;
    float4 v1 = *(const float4*)(p + 4);
    float f[8] = {v0.x, v0.y, v0.z, v0.w, v1.x, v1.y, v1.z, v1.w};
#pragma unroll
    for (int i = 0; i < 8; ++i) {
        unsigned short h = f2bf(f[i]);
        hi[i] = (short)h;
        lo[i] = (short)f2bf(f[i] - bf2f(h));
    }
}

// split 8 consecutive fp16 into hi/lo bf16 fragments — EXACT (11-bit fp16 mantissa <= 8+8)
__device__ __forceinline__ void split8h(const unsigned short* __restrict__ p, short8& hi, short8& lo) {
    uint4 v = *(const uint4*)p;
    unsigned int w[4] = {v.x, v.y, v.z, v.w};
#pragma unroll
    for (int i = 0; i < 4; ++i) {
#pragma unroll
        for (int j = 0; j < 2; ++j) {
            float f = h2f((unsigned short)((w[i] >> (j * 16)) & 0xffffu));
            unsigned short h = f2bf(f);
            hi[i * 2 + j] = (short)h;
            lo[i * 2 + j] = (short)f2bf(f - bf2f(h));
        }
    }
}

// ---- async stage ONE 32KB weight array into an LDS buffer (512 threads) ----
// entry e = (ct*4+ks)*64 + lane  holds  W[ct*16+(lane&15)][ks*32+(lane>>4)*8 .. +8]
typedef __attribute__((address_space(3))) unsigned short lds_us;
typedef __attribute__((address_space(1))) const unsigned short gl_us;

__device__ __forceinline__ void stageG(unsigned short* sWbuf,
                                       const unsigned short* __restrict__ W, int tid) {
#pragma unroll
    for (int i = 0; i < 4; ++i) {
        int e = tid + 512 * i;
        int ct = e >> 8;
        int ks = (e >> 6) & 3;
        int q = (e >> 4) & 3;
        int l = e & 15;
        const unsigned short* g = W + (size_t)(ct * 16 + l) * D + ks * 32 + q * 8;
        unsigned short* lp = sWbuf + (size_t)(i * 512 + (tid & ~63)) * 8;
        __builtin_amdgcn_global_load_lds((gl_us*)g, (lds_us*)lp, 16, 0, 0);
    }
}

// one full pass over a staged 32KB weight array: 4ks x 8ct fragments
template <bool DUAL>
__device__ __forceinline__ void computeP(const unsigned short* sWbuf, int lane,
                                         const short8* Ah, const short8* Al, floatx4* acc) {
#pragma unroll
    for (int ks = 0; ks < 4; ++ks)
#pragma unroll
        for (int ct = 0; ct < 8; ++ct) {
            short8 wf = *(const short8*)(sWbuf + ((ct * 4 + ks) * 64 + lane) * 8);
            acc[ct] = __builtin_amdgcn_mfma_f32_16x16x32_bf16(Ah[ks], wf, acc[ct], 0, 0, 0);
            if (DUAL)
                acc[ct] = __builtin_amdgcn_mfma_f32_16x16x32_bf16(Al[ks], wf, acc[ct], 0, 0, 0);
        }
}

// ---------------- cooperative CSR+prep mega-kernel (replaces 5 launches) ----------------
// phases: zero bcnt | cvt splits + xf + bucket hist | bscan | bucket scatter | build
__device__ __forceinline__ void cvt1(const float* __restrict__ s,
                                     unsigned short* __restrict__ hi,
                                     unsigned short* __restrict__ lo, int i) {
    float4 v = ((const float4*)s)[i];
    float f[4] = {v.x, v.y, v.z, v.w};
    ushort4 h, l;
    unsigned short* hp = (unsigned short*)&h;
    unsigned short* lp = (unsigned short*)&l;
#pragma unroll
    for (int c = 0; c < 4; ++c) {
        unsigned short hh = f2bf(f[c]);
        hp[c] = hh;
        lp[c] = f2bf(f[c] - bf2f(hh));
    }
    ((ushort4*)hi)[i] = h;
    ((ushort4*)lo)[i] = l;
}

__global__ __launch_bounds__(512) void k_csr(
    const float* __restrict__ WlAll, unsigned short* __restrict__ Wlh, unsigned short* __restrict__ Wll,
    const float* __restrict__ WrAll, unsigned short* __restrict__ Wrh, unsigned short* __restrict__ Wrl,
    const float* __restrict__ projW, unsigned short* __restrict__ pWh, unsigned short* __restrict__ pWl,
    const float* __restrict__ x, unsigned short* __restrict__ xf,
    const int* __restrict__ src, const int* __restrict__ dst,
    int* __restrict__ bcnt, int* __restrict__ bbase, int* __restrict__ bcur,
    uint2* __restrict__ pairs, int* __restrict__ offs, float* __restrict__ invd,
    int* __restrict__ csr_src) {
    cg::grid_group grid = cg::this_grid();
    __shared__ int sh[1024];
    int tid = threadIdx.x;
    int nb = gridDim.x;                 // NBKT
    int gstr = nb * 512;

    // phase 0: zero the global bucket histogram
    if (blockIdx.x == 0) bcnt[tid] = 0;
    grid.sync();

    // phase 1: weight splits + x->fp16 (grid-stride) + LDS-reduced bucket histogram
    for (int i = blockIdx.x * 512 + tid; i < 3 * D * D / 4; i += gstr) cvt1(WlAll, Wlh, Wll, i);
    for (int i = blockIdx.x * 512 + tid; i < 3 * D * D / 4; i += gstr) cvt1(WrAll, Wrh, Wrl, i);
    for (int i = blockIdx.x * 512 + tid; i < D * D / 4; i += gstr) cvt1(projW, pWh, pWl, i);
    for (int i = blockIdx.x * 512 + tid; i < N_NODES * D / 4; i += gstr) {
        float4 v = ((const float4*)x)[i];
        ushort4 o;
        o.x = f2h(v.x); o.y = f2h(v.y); o.z = f2h(v.z); o.w = f2h(v.w);
        ((ushort4*)xf)[i] = o;
    }
    for (int i = tid; i < NBKT; i += 512) sh[i] = 0;
    __syncthreads();
    for (int e = blockIdx.x * 512 + tid; e < N_EDGES; e += gstr)
        atomicAdd(&sh[dst[e] >> 8], 1);
    __syncthreads();
    for (int i = tid; i < NBKT; i += 512) {
        int c = sh[i];
        if (c) atomicAdd(&bcnt[i], c);
    }
    grid.sync();

    // phase 2: bucket scan (block 0 only; 512-wide Hillis-Steele over 391 entries)
    if (blockIdx.x == 0) {
        int v = (tid < NBKT) ? bcnt[tid] : 0;
        sh[tid] = v;
        __syncthreads();
        for (int off = 1; off < 512; off <<= 1) {
            int t = (tid >= off) ? sh[tid - off] : 0;
            __syncthreads();
            if (tid >= off) sh[tid] += t;
            __syncthreads();
        }
        int ex = sh[tid] - v;
        if (tid < NBKT) {
            bbase[tid] = ex;
            bcur[tid] = ex;
        }
        if (tid == 0) {
            bbase[NBKT] = N_EDGES;
            offs[N_NODES] = N_EDGES;
        }
    }
    grid.sync();

    // phase 3: bucket scatter — block b handles edges [b*4096, b*4096+4096)
    {
        int* cnt = sh;
        int* off = sh + NBKT;
        for (int i = tid; i < NBKT; i += 512) cnt[i] = 0;
        __syncthreads();
        int e0 = blockIdx.x * 4096;
        int mydst[8], mysrc[8];
#pragma unroll
        for (int i = 0; i < 8; ++i) {
            int e = e0 + tid + i * 512;
            int d = (e < N_EDGES) ? dst[e] : -1;
            mydst[i] = d;
            mysrc[i] = (e < N_EDGES) ? src[e] : 0;
            if (d >= 0) atomicAdd(&cnt[d >> 8], 1);
        }
        __syncthreads();
        for (int b = tid; b < NBKT; b += 512) {
            int c = cnt[b];
            off[b] = c ? atomicAdd(&bcur[b], c) : 0;
        }
        __syncthreads();
#pragma unroll
        for (int i = 0; i < 8; ++i) {
            int d = mydst[i];
            if (d >= 0) {
                int p = atomicAdd(&off[d >> 8], 1);
                pairs[p] = make_uint2((unsigned)mysrc[i], (unsigned)d);
            }
        }
    }
    grid.sync();

    // phase 4: build — block b owns bucket b: LDS count -> scan -> offs/invd/csr
    {
        int* cnt = sh;
        int* scn = sh + 256;
        int* cur = sh + 512;
        int b = blockIdx.x;
        int node0 = b << 8;
        int nn = N_NODES - node0; if (nn > 256) nn = 256;
        int beg = bbase[b], end = bbase[b + 1];

        for (int i = tid; i < 256; i += 512) cnt[i] = 0;
        __syncthreads();
        for (int e = beg + tid; e < end; e += 512) atomicAdd(&cnt[pairs[e].y & 255u], 1);
        __syncthreads();
        int v = (tid < 256) ? cnt[tid] : 0;
        if (tid < 256) scn[tid] = v;
        __syncthreads();
        for (int off = 1; off < 256; off <<= 1) {
            int t = (tid >= off && tid < 256) ? scn[tid - off] : 0;
            __syncthreads();
            if (tid >= off && tid < 256) scn[tid] += t;
            __syncthreads();
        }
        if (tid < 256) {
            int start = beg + scn[tid] - v;
            if (tid < nn) {
                offs[node0 + tid] = start;
                invd[node0 + tid] = 1.0f / (float)(v > 1 ? v : 1);
            }
            cur[tid] = start;
        }
        __syncthreads();
        for (int e = beg + tid; e < end; e += 512) {
            uint2 pr = pairs[e];
            int p = atomicAdd(&cur[pr.y & 255u], 1);
            csr_src[p] = (int)pr.x;
        }
    }
}

// ---------------- mean aggregation: dual-node waves, fp16 gather -> fp16 agg --------
// sums in fp32, stores the mean rounded to fp16 (exact hi/lo-splittable downstream)
__global__ void k_agg_f16(const unsigned short* __restrict__ hf, const int* __restrict__ offs,
                          const int* __restrict__ csr_src, const float* __restrict__ inv_deg,
                          unsigned short* __restrict__ aggh) {
    int gw = (blockIdx.x * 256 + threadIdx.x) >> 6;   // global wave id
    int lane = threadIdx.x & 63;
    int half = lane >> 5, l32 = lane & 31;
    int node = gw * 2 + half;
    int beg = offs[node], end = offs[node + 1];
    float a0 = 0.f, a1 = 0.f, a2 = 0.f, a3 = 0.f;
    int e = beg;
    for (; e + 7 < end; e += 8) {
        int ss[8];
#pragma unroll
        for (int i = 0; i < 8; ++i) ss[i] = csr_src[e + i];
        uint2 vv[8];
#pragma unroll
        for (int i = 0; i < 8; ++i)
            vv[i] = ((const uint2*)(hf + (size_t)ss[i] * D))[l32];
#pragma unroll
        for (int i = 0; i < 8; ++i) {
            a0 += h2f((unsigned short)(vv[i].x & 0xffffu));
            a1 += h2f((unsigned short)(vv[i].x >> 16));
            a2 += h2f((unsigned short)(vv[i].y & 0xffffu));
            a3 += h2f((unsigned short)(vv[i].y >> 16));
        }
    }
    for (; e + 3 < end; e += 4) {
        int ss[4];
#pragma unroll
        for (int i = 0; i < 4; ++i) ss[i] = csr_src[e + i];
        uint2 vv[4];
#pragma unroll
        for (int i = 0; i < 4; ++i)
            vv[i] = ((const uint2*)(hf + (size_t)ss[i] * D))[l32];
#pragma unroll
        for (int i = 0; i < 4; ++i) {
            a0 += h2f((unsigned short)(vv[i].x & 0xffffu));
            a1 += h2f((unsigned short)(vv[i].x >> 16));
            a2 += h2f((unsigned short)(vv[i].y & 0xffffu));
            a3 += h2f((unsigned short)(vv[i].y >> 16));
        }
    }
    for (; e < end; ++e) {
        int s = csr_src[e];
        uint2 v = ((const uint2*)(hf + (size_t)s * D))[l32];
        a0 += h2f((unsigned short)(v.x & 0xffffu));
        a1 += h2f((unsigned short)(v.x >> 16));
        a2 += h2f((unsigned short)(v.y & 0xffffu));
        a3 += h2f((unsigned short)(v.y >> 16));
    }
    float id = inv_deg[node];
    ushort4 o;
    o.x = f2h(a0 * id); o.y = f2h(a1 * id); o.z = f2h(a2 * id); o.w = f2h(a3 * id);
    ((ushort4*)(aggh + (size_t)node * D))[l32] = o;
}

// ---------------- fused SAGE layer (r11-proven): fp16 hidden state AND fp16 agg -------
// MODE 0: hin = x (fp32); skip = x@projW^T+projB fused; writes houtf
// MODE 1: hin = skip = hinh (fp16); writes houtf
// MODE 2: hin = skip = hinh (fp16); fused head -> outp
template <int MODE>
__global__ __launch_bounds__(512) void k_layer(
    const unsigned short* __restrict__ aggh,   // fp16 agg
    const float* __restrict__ xinf,            // MODE 0 only (fp32 x)
    const unsigned short* __restrict__ hinh,   // modes 1/2 (fp16 h)
    const unsigned short* __restrict__ Wlh, const unsigned short* __restrict__ Wll,
    const unsigned short* __restrict__ Wrh, const unsigned short* __restrict__ Wrl,
    const unsigned short* __restrict__ pWh, const unsigned short* __restrict__ pWl,
    const float* __restrict__ projB,
    const float* __restrict__ lb, const float* __restrict__ g,
    const float* __restrict__ beta,
    unsigned short* __restrict__ houtf,
    const float* __restrict__ hw, const float* __restrict__ hb_bias,
    const float* __restrict__ rr, const float* __restrict__ alphap,
    float* __restrict__ outp) {
    __shared__ unsigned short sW[2][16384];   // 2 x 32KB double buffer

    int tid = threadIdx.x;
    int w = tid >> 6, lane = tid & 63;
    int quad = lane >> 4, l16 = lane & 15;
    int base = blockIdx.x * 128 + w * 16;

    int ar = base + l16; if (ar > N_NODES - 1) ar = N_NODES - 1;
    int koff = quad * 8;

    floatx4 z = {0.f, 0.f, 0.f, 0.f};
    floatx4 acc[8];
#pragma unroll
    for (int ct = 0; ct < 8; ++ct) acc[ct] = z;

    // prologue: async-stage Wl_hi into buf0; split agg (fp16, exact) under in-flight loads
    stageG(sW[0], Wlh, tid);
    short8 ah[4], al[4];
#pragma unroll
    for (int ks = 0; ks < 4; ++ks) split8h(aggh + (size_t)ar * D + ks * 32 + koff, ah[ks], al[ks]);
    __syncthreads();

    // phase 1: stage Wl_lo | compute Wl_hi (A_hi*W_hi + A_lo*W_hi)
    stageG(sW[1], Wll, tid);
    computeP<true>(sW[0], lane, ah, al, acc);
    __syncthreads();

    // phase 2: stage Wr_hi; split hin | compute Wl_lo (A_hi*W_lo)
    stageG(sW[0], Wrh, tid);
    short8 bh[4], blo[4];
#pragma unroll
    for (int ks = 0; ks < 4; ++ks) {
        if (MODE == 0) split8(xinf + (size_t)ar * D + ks * 32 + koff, bh[ks], blo[ks]);
        else           split8h(hinh + (size_t)ar * D + ks * 32 + koff, bh[ks], blo[ks]);
    }
    computeP<false>(sW[1], lane, ah, al, acc);
    __syncthreads();

    // phase 3: stage Wr_lo | compute Wr_hi
    stageG(sW[1], Wrl, tid);
    computeP<true>(sW[0], lane, bh, blo, acc);
    __syncthreads();

    // phase 4: (MODE0: stage proj_hi) | compute Wr_lo
    if (MODE == 0) stageG(sW[0], pWh, tid);
    computeP<false>(sW[1], lane, bh, blo, acc);

    floatx4 accR[8];
    if (MODE == 0) {
#pragma unroll
        for (int ct = 0; ct < 8; ++ct) accR[ct] = z;
        __syncthreads();
        // phase 5: stage proj_lo | compute proj_hi
        stageG(sW[1], pWl, tid);
        computeP<true>(sW[0], lane, bh, blo, accR);
        __syncthreads();
        // phase 6: compute proj_lo
        computeP<false>(sW[1], lane, bh, blo, accR);
    }

    // bias + relu in-register
    float lbv[8], gv[8], bv[8];
#pragma unroll
    for (int ct = 0; ct < 8; ++ct) {
        int n = ct * 16 + l16;
        lbv[ct] = lb[n];
        gv[ct] = g[n];
        bv[ct] = beta[n];
    }
#pragma unroll
    for (int ct = 0; ct < 8; ++ct)
#pragma unroll
        for (int r = 0; r < 4; ++r)
            acc[ct][r] = fmaxf(acc[ct][r] + lbv[ct], 0.f);

    // LN stats per row (row = quad*4+r), in-register
    float mu[4], rs[4];
#pragma unroll
    for (int r = 0; r < 4; ++r) {
        float s = 0.f, ss = 0.f;
#pragma unroll
        for (int ct = 0; ct < 8; ++ct) {
            float v = acc[ct][r];
            s += v;
            ss += v * v;
        }
#pragma unroll
        for (int m = 1; m < 16; m <<= 1) {
            s += __shfl_xor(s, m, 64);
            ss += __shfl_xor(ss, m, 64);
        }
        float m_ = s * (1.0f / 128.0f);
        float v_ = ss * (1.0f / 128.0f) - m_ * m_;
        mu[r] = m_;
        rs[r] = rsqrtf(v_ + 1e-5f);
    }

    float pbv[8], hwv[8];
    if (MODE == 0) {
#pragma unroll
        for (int ct = 0; ct < 8; ++ct) pbv[ct] = projB[ct * 16 + l16];
    }
    if (MODE == 2) {
#pragma unroll
        for (int ct = 0; ct < 8; ++ct) hwv[ct] = hw[ct * 16 + l16];
    }

    // epilogue — skip from fp16 h (modes 1/2) or fused proj (mode 0); fp16-only h out
#pragma unroll
    for (int r = 0; r < 4; ++r) {
        int crow = base + quad * 4 + r;
        bool valid = (crow < N_NODES);
        float m_ = mu[r], rs_ = rs[r];
        size_t ro = (size_t)crow * D;
        if (MODE == 2) {
            float s = 0.f;
#pragma unroll
            for (int ct = 0; ct < 8; ++ct) {
                int col = ct * 16 + l16;
                float sk = valid ? h2f(hinh[ro + col]) : 0.f;
                float o = (acc[ct][r] - m_) * rs_ * gv[ct] + bv[ct] + sk;
                s += o * hwv[ct];
            }
#pragma unroll
            for (int m = 1; m < 16; m <<= 1) s += __shfl_xor(s, m, 64);
            if (l16 == 0 && valid) {
                float a = 1.0f / (1.0f + expf(-alphap[0]));
                outp[crow] = a * rr[crow] + (1.0f - a) * (s + hb_bias[0]);
            }
        } else {
            if (!valid) continue;
#pragma unroll
            for (int ct = 0; ct < 8; ++ct) {
                int col = ct * 16 + l16;
                float sk = (MODE == 0) ? (accR[ct][r] + pbv[ct]) : h2f(hinh[ro + col]);
                float o = (acc[ct][r] - m_) * rs_ * gv[ct] + bv[ct] + sk;
                houtf[ro + col] = f2h(o);
            }
        }
    }
}

// ---------------- launch ----------------
extern "C" void kernel_launch(void* const* d_in, const int* in_sizes, int n_in,
                              void* d_out, int out_size, void* d_ws, size_t ws_size,
                              hipStream_t stream) {
    const float* x     = (const float*)d_in[0];
    const int*   ei    = (const int*)d_in[1];
    const float* rr    = (const float*)d_in[2];
    const float* projW = (const float*)d_in[3];
    const float* projB = (const float*)d_in[4];
    const float* WlAll = (const float*)d_in[5];
    const float* lbAll = (const float*)d_in[6];
    const float* WrAll = (const float*)d_in[7];
    const float* gAll  = (const float*)d_in[8];
    const float* btAll = (const float*)d_in[9];
    const float* hw    = (const float*)d_in[10];
    const float* hbias = (const float*)d_in[11];
    const float* alpha = (const float*)d_in[12];
    float* out = (float*)d_out;

    char* p = (char*)d_ws;
    unsigned short* aggh = (unsigned short*)p; p += (size_t)N_NODES * D * 2;
    unsigned short* xf   = (unsigned short*)p; p += (size_t)N_NODES * D * 2;
    unsigned short* h0f  = (unsigned short*)p; p += (size_t)N_NODES * D * 2;
    unsigned short* h1f  = (unsigned short*)p; p += (size_t)N_NODES * D * 2;
    uint2* pairs = (uint2*)p; p += (size_t)N_EDGES * 8;
    unsigned short* Wlh = (unsigned short*)p; p += (size_t)3 * D * D * 2;
    unsigned short* Wll = (unsigned short*)p; p += (size_t)3 * D * D * 2;
    unsigned short* Wrh = (unsigned short*)p; p += (size_t)3 * D * D * 2;
    unsigned short* Wrl = (unsigned short*)p; p += (size_t)3 * D * D * 2;
    unsigned short* pWh = (unsigned short*)p; p += (size_t)D * D * 2;
    unsigned short* pWl = (unsigned short*)p; p += (size_t)D * D * 2;
    float* invd  = (float*)p; p += (size_t)N_NODES * 4;
    int* offs    = (int*)p; p += (size_t)(N_NODES + 2) * 4;
    int* csr_src = (int*)p; p += (size_t)N_EDGES * 4;
    int* bcnt    = (int*)p; p += 512 * 4;
    int* bbase   = (int*)p; p += 512 * 4;
    int* bcur    = (int*)p; p += 512 * 4;

    const int* src = ei;
    const int* dst = ei + N_EDGES;

    // cooperative CSR+prep mega-kernel (replaces memset + 4 kernels)
    {
        void* args[] = {
            (void*)&WlAll, (void*)&Wlh, (void*)&Wll,
            (void*)&WrAll, (void*)&Wrh, (void*)&Wrl,
            (void*)&projW, (void*)&pWh, (void*)&pWl,
            (void*)&x, (void*)&xf,
            (void*)&src, (void*)&dst,
            (void*)&bcnt, (void*)&bbase, (void*)&bcur,
            (void*)&pairs, (void*)&offs, (void*)&invd, (void*)&csr_src
        };
        hipLaunchCooperativeKernel((void*)k_csr, dim3(NBKT), dim3(512), args, 0, stream);
    }

    int gl = (N_NODES + 127) / 128;      // 782 blocks of 512 threads (128 rows each)
    int ga = N_NODES / 2 / 4;            // 12500 blocks (2 nodes per wave, 4 waves/block)

    // layer 0: h = x (fp32); skip = x@projW^T+projB fused; writes h0f (fp16 only)
    k_agg_f16<<<ga, 256, 0, stream>>>(xf, offs, csr_src, invd, aggh);
    k_layer<0><<<gl, 512, 0, stream>>>(aggh, x, nullptr,
                                       Wlh, Wll, Wrh, Wrl, pWh, pWl, projB,
                                       lbAll, gAll, btAll, h0f,
                                       nullptr, nullptr, nullptr, nullptr, nullptr);
    // layer 1: hin = skip = h0f (fp16); writes h1f
    k_agg_f16<<<ga, 256, 0, stream>>>(h0f, offs, csr_src, invd, aggh);
    k_layer<1><<<gl, 512, 0, stream>>>(aggh, nullptr, h0f,
                                       Wlh + D * D, Wll + D * D, Wrh + D * D, Wrl + D * D,
                                       nullptr, nullptr, nullptr,
                                       lbAll + D, gAll + D, btAll + D, h1f,
                                       nullptr, nullptr, nullptr, nullptr, nullptr);
    // layer 2: hin = skip = h1f (fp16); fused head -> out
    k_agg_f16<<<ga, 256, 0, stream>>>(h1f, offs, csr_src, invd, aggh);
    k_layer<2><<<gl, 512, 0, stream>>>(aggh, nullptr, h1f,
                                       Wlh + 2 * D * D, Wll + 2 * D * D,
                                       Wrh + 2 * D * D, Wrl + 2 * D * D,
                                       nullptr, nullptr, nullptr,
                                       lbAll + 2 * D, gAll + 2 * D, btAll + 2 * D,
                                       nullptr,
                                       hw, hbias, rr, alpha, out);
}

// Round 13
// 500.289 us; speedup vs baseline: 1.3724x; 1.3724x over previous
//
#include <hip/hip_runtime.h>
#include <math.h>

#define N_NODES 100000
#define N_EDGES 1600000
#define D 128
#define NBKT 391   // ceil(N_NODES/256) buckets of 256 dst nodes

// k_prep grid partition
#define PREP_WL 48     // 3*D*D/4 / 256
#define PREP_WR 48
#define PREP_PJ 16     // D*D/4 / 256
#define PREP_X  12500  // N_NODES*D/4 / 256
#define PREP_BC 391    // edge-count blocks (4096 edges each)

typedef __attribute__((ext_vector_type(8))) _Float16 half8;
typedef __attribute__((ext_vector_type(4))) float floatx4;

__device__ __forceinline__ unsigned short f2h(float f) {
    union { _Float16 h; unsigned short u; } c;
    c.h = (_Float16)f;
    return c.u;
}
__device__ __forceinline__ float h2f(unsigned short u) {
    union { unsigned short u; _Float16 h; } c;
    c.u = u;
    return (float)c.h;
}

// ---- async stage ONE 32KB weight array into an LDS buffer (512 threads) ----
// entry e = (ct*4+ks)*64 + lane  holds  W[ct*16+(lane&15)][ks*32+(lane>>4)*8 .. +8]
typedef __attribute__((address_space(3))) unsigned short lds_us;
typedef __attribute__((address_space(1))) const unsigned short gl_us;

__device__ __forceinline__ void stageG(unsigned short* sWbuf,
                                       const unsigned short* __restrict__ W, int tid) {
#pragma unroll
    for (int i = 0; i < 4; ++i) {
        int e = tid + 512 * i;
        int ct = e >> 8;
        int ks = (e >> 6) & 3;
        int q = (e >> 4) & 3;
        int l = e & 15;
        const unsigned short* g = W + (size_t)(ct * 16 + l) * D + ks * 32 + q * 8;
        unsigned short* lp = sWbuf + (size_t)(i * 512 + (tid & ~63)) * 8;
        __builtin_amdgcn_global_load_lds((gl_us*)g, (lds_us*)lp, 16, 0, 0);
    }
}

// one full pass over a staged 32KB fp16 weight array: 4ks x 8ct fragments, f16 MFMA
__device__ __forceinline__ void computeP16(const unsigned short* sWbuf, int lane,
                                           const half8* A, floatx4* acc) {
#pragma unroll
    for (int ks = 0; ks < 4; ++ks)
#pragma unroll
        for (int ct = 0; ct < 8; ++ct) {
            half8 wf = *(const half8*)(sWbuf + ((ct * 4 + ks) * 64 + lane) * 8);
            acc[ct] = __builtin_amdgcn_mfma_f32_16x16x32_f16(A[ks], wf, acc[ct], 0, 0, 0);
        }
}

// ---------------- merged preprocessing: fp16 weight splits + x->fp16 + bucket hist ----
// W = W_h (fp16 RNE) + W_l (fp16 of residual): ~20+ bit effective weight precision
__device__ __forceinline__ void cvt_split_body(const float* __restrict__ s,
                                               unsigned short* __restrict__ hi,
                                               unsigned short* __restrict__ lo,
                                               int lb, int n4, int tid) {
    int i = lb * 256 + tid;
    if (i < n4) {
        float4 v = ((const float4*)s)[i];
        float f[4] = {v.x, v.y, v.z, v.w};
        ushort4 h, l;
        unsigned short* hp = (unsigned short*)&h;
        unsigned short* lp = (unsigned short*)&l;
#pragma unroll
        for (int c = 0; c < 4; ++c) {
            unsigned short hh = f2h(f[c]);
            hp[c] = hh;
            lp[c] = f2h(f[c] - h2f(hh));
        }
        ((ushort4*)hi)[i] = h;
        ((ushort4*)lo)[i] = l;
    }
}

__global__ __launch_bounds__(256) void k_prep(
    const float* __restrict__ WlAll, unsigned short* __restrict__ Wlh, unsigned short* __restrict__ Wll,
    const float* __restrict__ WrAll, unsigned short* __restrict__ Wrh, unsigned short* __restrict__ Wrl,
    const float* __restrict__ projW, unsigned short* __restrict__ pWh, unsigned short* __restrict__ pWl,
    const float* __restrict__ x, unsigned short* __restrict__ xf,
    const int* __restrict__ dst, int* __restrict__ bcnt) {
    __shared__ int h[NBKT];
    int tid = threadIdx.x;
    int b = blockIdx.x;
    if (b < PREP_WL) { cvt_split_body(WlAll, Wlh, Wll, b, 3 * D * D / 4, tid); return; }
    b -= PREP_WL;
    if (b < PREP_WR) { cvt_split_body(WrAll, Wrh, Wrl, b, 3 * D * D / 4, tid); return; }
    b -= PREP_WR;
    if (b < PREP_PJ) { cvt_split_body(projW, pWh, pWl, b, D * D / 4, tid); return; }
    b -= PREP_PJ;
    if (b < PREP_X) {
        int i = b * 256 + tid;
        if (i < N_NODES * D / 4) {
            float4 v = ((const float4*)x)[i];
            ushort4 o;
            o.x = f2h(v.x); o.y = f2h(v.y); o.z = f2h(v.z); o.w = f2h(v.w);
            ((ushort4*)xf)[i] = o;
        }
        return;
    }
    b -= PREP_X;
    // bucket histogram section: 4096 edges per block, LDS-reduced
    for (int i = tid; i < NBKT; i += 256) h[i] = 0;
    __syncthreads();
    int e0 = b * 4096;
#pragma unroll
    for (int i = 0; i < 16; ++i) {
        int e = e0 + tid + i * 256;
        if (e < N_EDGES) atomicAdd(&h[dst[e] >> 8], 1);
    }
    __syncthreads();
    for (int i = tid; i < NBKT; i += 256) {
        int c = h[i];
        if (c) atomicAdd(&bcnt[i], c);
    }
}

// ---------------- bucket scan: 391 counts -> bases + cursors (1 block) ----------------
__global__ void k_bscan(const int* __restrict__ bcnt, int* __restrict__ bbase,
                        int* __restrict__ bcur, int* __restrict__ offs) {
    __shared__ int tmp[512];
    int tid = threadIdx.x;
    int v = (tid < NBKT) ? bcnt[tid] : 0;
    tmp[tid] = v;
    __syncthreads();
    for (int off = 1; off < 512; off <<= 1) {
        int t = (tid >= off) ? tmp[tid - off] : 0;
        __syncthreads();
        if (tid >= off) tmp[tid] += t;
        __syncthreads();
    }
    int ex = tmp[tid] - v;   // exclusive prefix
    if (tid < NBKT) {
        bbase[tid] = ex;
        bcur[tid] = ex;
    }
    if (tid == 0) {
        bbase[NBKT] = N_EDGES;
        offs[N_NODES] = N_EDGES;
    }
}

// pass A: scatter (src,dst) pairs bucket-contiguous (dst>>8 buckets)
__global__ __launch_bounds__(256) void k_bucket(const int* __restrict__ src,
                                                const int* __restrict__ dst,
                                                int* __restrict__ bcur, uint2* __restrict__ pairs) {
    __shared__ int cnt[NBKT];
    __shared__ int off[NBKT];
    int tid = threadIdx.x;
    for (int i = tid; i < NBKT; i += 256) cnt[i] = 0;
    __syncthreads();
    int e0 = blockIdx.x * 4096;
    int mydst[16], mysrc[16];
#pragma unroll
    for (int i = 0; i < 16; ++i) {
        int e = e0 + tid + i * 256;
        int d = (e < N_EDGES) ? dst[e] : -1;
        mydst[i] = d;
        mysrc[i] = (e < N_EDGES) ? src[e] : 0;
        if (d >= 0) atomicAdd(&cnt[d >> 8], 1);
    }
    __syncthreads();
    for (int b = tid; b < NBKT; b += 256) {
        int c = cnt[b];
        off[b] = c ? atomicAdd(&bcur[b], c) : 0;
    }
    __syncthreads();
#pragma unroll
    for (int i = 0; i < 16; ++i) {
        int d = mydst[i];
        if (d >= 0) {
            int p = atomicAdd(&off[d >> 8], 1);
            pairs[p] = make_uint2((unsigned)mysrc[i], (unsigned)d);
        }
    }
}

// pass B: per bucket — LDS count + scan -> offs/invd/csr, all cursors in LDS
__global__ __launch_bounds__(256) void k_build(const uint2* __restrict__ pairs,
                                               const int* __restrict__ bbase,
                                               int* __restrict__ offs, float* __restrict__ invd,
                                               int* __restrict__ csr_src) {
    __shared__ int cnt[256];
    __shared__ int scn[256];
    __shared__ int cur[256];
    int b = blockIdx.x, tid = threadIdx.x;
    int node0 = b << 8;
    int nn = N_NODES - node0; if (nn > 256) nn = 256;
    int beg = bbase[b], end = bbase[b + 1];

    cnt[tid] = 0;
    __syncthreads();
    for (int e = beg + tid; e < end; e += 256) atomicAdd(&cnt[pairs[e].y & 255u], 1);
    __syncthreads();
    int v = cnt[tid];
    scn[tid] = v;
    __syncthreads();
    for (int off = 1; off < 256; off <<= 1) {
        int t = (tid >= off) ? scn[tid - off] : 0;
        __syncthreads();
        if (tid >= off) scn[tid] += t;
        __syncthreads();
    }
    int start = beg + scn[tid] - v;   // global start of this node's edge range
    if (tid < nn) {
        offs[node0 + tid] = start;
        invd[node0 + tid] = 1.0f / (float)(v > 1 ? v : 1);
    }
    cur[tid] = start;
    __syncthreads();
    for (int e = beg + tid; e < end; e += 256) {
        uint2 pr = pairs[e];
        int p = atomicAdd(&cur[pr.y & 255u], 1);
        csr_src[p] = (int)pr.x;
    }
}

// ---------------- mean aggregation: dual-node waves, fp16 gather -> fp16 agg --------
// sums in fp32, stores the mean rounded to fp16
__global__ void k_agg_f16(const unsigned short* __restrict__ hf, const int* __restrict__ offs,
                          const int* __restrict__ csr_src, const float* __restrict__ inv_deg,
                          unsigned short* __restrict__ aggh) {
    int gw = (blockIdx.x * 256 + threadIdx.x) >> 6;   // global wave id
    int lane = threadIdx.x & 63;
    int half = lane >> 5, l32 = lane & 31;
    int node = gw * 2 + half;
    int beg = offs[node], end = offs[node + 1];
    float a0 = 0.f, a1 = 0.f, a2 = 0.f, a3 = 0.f;
    int e = beg;
    for (; e + 7 < end; e += 8) {
        int ss[8];
#pragma unroll
        for (int i = 0; i < 8; ++i) ss[i] = csr_src[e + i];
        uint2 vv[8];
#pragma unroll
        for (int i = 0; i < 8; ++i)
            vv[i] = ((const uint2*)(hf + (size_t)ss[i] * D))[l32];
#pragma unroll
        for (int i = 0; i < 8; ++i) {
            a0 += h2f((unsigned short)(vv[i].x & 0xffffu));
            a1 += h2f((unsigned short)(vv[i].x >> 16));
            a2 += h2f((unsigned short)(vv[i].y & 0xffffu));
            a3 += h2f((unsigned short)(vv[i].y >> 16));
        }
    }
    for (; e + 3 < end; e += 4) {
        int ss[4];
#pragma unroll
        for (int i = 0; i < 4; ++i) ss[i] = csr_src[e + i];
        uint2 vv[4];
#pragma unroll
        for (int i = 0; i < 4; ++i)
            vv[i] = ((const uint2*)(hf + (size_t)ss[i] * D))[l32];
#pragma unroll
        for (int i = 0; i < 4; ++i) {
            a0 += h2f((unsigned short)(vv[i].x & 0xffffu));
            a1 += h2f((unsigned short)(vv[i].x >> 16));
            a2 += h2f((unsigned short)(vv[i].y & 0xffffu));
            a3 += h2f((unsigned short)(vv[i].y >> 16));
        }
    }
    for (; e < end; ++e) {
        int s = csr_src[e];
        uint2 v = ((const uint2*)(hf + (size_t)s * D))[l32];
        a0 += h2f((unsigned short)(v.x & 0xffffu));
        a1 += h2f((unsigned short)(v.x >> 16));
        a2 += h2f((unsigned short)(v.y & 0xffffu));
        a3 += h2f((unsigned short)(v.y >> 16));
    }
    float id = inv_deg[node];
    ushort4 o;
    o.x = f2h(a0 * id); o.y = f2h(a1 * id); o.z = f2h(a2 * id); o.w = f2h(a3 * id);
    ((ushort4*)(aggh + (size_t)node * D))[l32] = o;
}

// ---------------- fused SAGE layer v13: native f16 MFMA, fp16-pair weights ----------
// Activations (agg, h, xf) are exact fp16 -> loaded directly as A-fragments (no split).
// W = W_h + W_l (fp16 pair) -> 2 single MFMA passes per weight matrix (was 3).
// MODE 0: hin = xf (fp16); skip = x@projW^T+projB fused (2 proj passes); writes houtf
// MODE 1: hin = skip = hinh (fp16); writes houtf
// MODE 2: hin = skip = hinh (fp16); fused head -> outp
template <int MODE>
__global__ __launch_bounds__(512) void k_layer(
    const unsigned short* __restrict__ aggh,   // fp16 agg
    const unsigned short* __restrict__ hinh,   // fp16 h (or xf in MODE 0)
    const unsigned short* __restrict__ Wlh, const unsigned short* __restrict__ Wll,
    const unsigned short* __restrict__ Wrh, const unsigned short* __restrict__ Wrl,
    const unsigned short* __restrict__ pWh, const unsigned short* __restrict__ pWl,
    const float* __restrict__ projB,
    const float* __restrict__ lb, const float* __restrict__ g,
    const float* __restrict__ beta,
    unsigned short* __restrict__ houtf,
    const float* __restrict__ hw, const float* __restrict__ hb_bias,
    const float* __restrict__ rr, const float* __restrict__ alphap,
    float* __restrict__ outp) {
    __shared__ unsigned short sW[2][16384];   // 2 x 32KB double buffer

    int tid = threadIdx.x;
    int w = tid >> 6, lane = tid & 63;
    int quad = lane >> 4, l16 = lane & 15;
    int base = blockIdx.x * 128 + w * 16;

    int ar = base + l16; if (ar > N_NODES - 1) ar = N_NODES - 1;
    int koff = quad * 8;

    floatx4 z = {0.f, 0.f, 0.f, 0.f};
    floatx4 acc[8];
#pragma unroll
    for (int ct = 0; ct < 8; ++ct) acc[ct] = z;

    // prologue: async-stage Wl_h into buf0; load A-frags (direct fp16) under in-flight loads
    stageG(sW[0], Wlh, tid);
    half8 ah[4];
#pragma unroll
    for (int ks = 0; ks < 4; ++ks)
        ah[ks] = *(const half8*)(aggh + (size_t)ar * D + ks * 32 + koff);
    __syncthreads();

    // phase 1: stage Wl_l | compute A*Wl_h
    stageG(sW[1], Wll, tid);
    computeP16(sW[0], lane, ah, acc);
    __syncthreads();

    // phase 2: stage Wr_h; load B-frags | compute A*Wl_l
    stageG(sW[0], Wrh, tid);
    half8 bh[4];
#pragma unroll
    for (int ks = 0; ks < 4; ++ks)
        bh[ks] = *(const half8*)(hinh + (size_t)ar * D + ks * 32 + koff);
    computeP16(sW[1], lane, ah, acc);
    __syncthreads();

    // phase 3: stage Wr_l | compute B*Wr_h
    stageG(sW[1], Wrl, tid);
    computeP16(sW[0], lane, bh, acc);
    __syncthreads();

    // phase 4: (MODE0: stage proj_h) | compute B*Wr_l
    if (MODE == 0) stageG(sW[0], pWh, tid);
    computeP16(sW[1], lane, bh, acc);

    floatx4 accR[8];
    if (MODE == 0) {
#pragma unroll
        for (int ct = 0; ct < 8; ++ct) accR[ct] = z;
        __syncthreads();
        // phase 5: stage proj_l | compute B*proj_h
        stageG(sW[1], pWl, tid);
        computeP16(sW[0], lane, bh, accR);
        __syncthreads();
        // phase 6: compute B*proj_l
        computeP16(sW[1], lane, bh, accR);
    }

    // bias + relu in-register
    float lbv[8], gv[8], bv[8];
#pragma unroll
    for (int ct = 0; ct < 8; ++ct) {
        int n = ct * 16 + l16;
        lbv[ct] = lb[n];
        gv[ct] = g[n];
        bv[ct] = beta[n];
    }
#pragma unroll
    for (int ct = 0; ct < 8; ++ct)
#pragma unroll
        for (int r = 0; r < 4; ++r)
            acc[ct][r] = fmaxf(acc[ct][r] + lbv[ct], 0.f);

    // LN stats per row (row = quad*4+r), in-register
    float mu[4], rs[4];
#pragma unroll
    for (int r = 0; r < 4; ++r) {
        float s = 0.f, ss = 0.f;
#pragma unroll
        for (int ct = 0; ct < 8; ++ct) {
            float v = acc[ct][r];
            s += v;
            ss += v * v;
        }
#pragma unroll
        for (int m = 1; m < 16; m <<= 1) {
            s += __shfl_xor(s, m, 64);
            ss += __shfl_xor(ss, m, 64);
        }
        float m_ = s * (1.0f / 128.0f);
        float v_ = ss * (1.0f / 128.0f) - m_ * m_;
        mu[r] = m_;
        rs[r] = rsqrtf(v_ + 1e-5f);
    }

    float pbv[8], hwv[8];
    if (MODE == 0) {
#pragma unroll
        for (int ct = 0; ct < 8; ++ct) pbv[ct] = projB[ct * 16 + l16];
    }
    if (MODE == 2) {
#pragma unroll
        for (int ct = 0; ct < 8; ++ct) hwv[ct] = hw[ct * 16 + l16];
    }

    // epilogue — skip from fp16 h (modes 1/2) or fused proj (mode 0); fp16-only h out
#pragma unroll
    for (int r = 0; r < 4; ++r) {
        int crow = base + quad * 4 + r;
        bool valid = (crow < N_NODES);
        float m_ = mu[r], rs_ = rs[r];
        size_t ro = (size_t)crow * D;
        if (MODE == 2) {
            float s = 0.f;
#pragma unroll
            for (int ct = 0; ct < 8; ++ct) {
                int col = ct * 16 + l16;
                float sk = valid ? h2f(hinh[ro + col]) : 0.f;
                float o = (acc[ct][r] - m_) * rs_ * gv[ct] + bv[ct] + sk;
                s += o * hwv[ct];
            }
#pragma unroll
            for (int m = 1; m < 16; m <<= 1) s += __shfl_xor(s, m, 64);
            if (l16 == 0 && valid) {
                float a = 1.0f / (1.0f + expf(-alphap[0]));
                outp[crow] = a * rr[crow] + (1.0f - a) * (s + hb_bias[0]);
            }
        } else {
            if (!valid) continue;
#pragma unroll
            for (int ct = 0; ct < 8; ++ct) {
                int col = ct * 16 + l16;
                float sk = (MODE == 0) ? (accR[ct][r] + pbv[ct]) : h2f(hinh[ro + col]);
                float o = (acc[ct][r] - m_) * rs_ * gv[ct] + bv[ct] + sk;
                houtf[ro + col] = f2h(o);
            }
        }
    }
}

// ---------------- launch ----------------
extern "C" void kernel_launch(void* const* d_in, const int* in_sizes, int n_in,
                              void* d_out, int out_size, void* d_ws, size_t ws_size,
                              hipStream_t stream) {
    const float* x     = (const float*)d_in[0];
    const int*   ei    = (const int*)d_in[1];
    const float* rr    = (const float*)d_in[2];
    const float* projW = (const float*)d_in[3];
    const float* projB = (const float*)d_in[4];
    const float* WlAll = (const float*)d_in[5];
    const float* lbAll = (const float*)d_in[6];
    const float* WrAll = (const float*)d_in[7];
    const float* gAll  = (const float*)d_in[8];
    const float* btAll = (const float*)d_in[9];
    const float* hw    = (const float*)d_in[10];
    const float* hbias = (const float*)d_in[11];
    const float* alpha = (const float*)d_in[12];
    float* out = (float*)d_out;

    char* p = (char*)d_ws;
    unsigned short* aggh = (unsigned short*)p; p += (size_t)N_NODES * D * 2;
    unsigned short* xf   = (unsigned short*)p; p += (size_t)N_NODES * D * 2;
    unsigned short* h0f  = (unsigned short*)p; p += (size_t)N_NODES * D * 2;
    unsigned short* h1f  = (unsigned short*)p; p += (size_t)N_NODES * D * 2;
    uint2* pairs = (uint2*)p; p += (size_t)N_EDGES * 8;
    unsigned short* Wlh = (unsigned short*)p; p += (size_t)3 * D * D * 2;
    unsigned short* Wll = (unsigned short*)p; p += (size_t)3 * D * D * 2;
    unsigned short* Wrh = (unsigned short*)p; p += (size_t)3 * D * D * 2;
    unsigned short* Wrl = (unsigned short*)p; p += (size_t)3 * D * D * 2;
    unsigned short* pWh = (unsigned short*)p; p += (size_t)D * D * 2;
    unsigned short* pWl = (unsigned short*)p; p += (size_t)D * D * 2;
    float* invd  = (float*)p; p += (size_t)N_NODES * 4;
    int* offs    = (int*)p; p += (size_t)(N_NODES + 2) * 4;
    int* csr_src = (int*)p; p += (size_t)N_EDGES * 4;
    int* bcnt    = (int*)p; p += 512 * 4;
    int* bbase   = (int*)p; p += 512 * 4;
    int* bcur    = (int*)p; p += 512 * 4;

    const int* src = ei;
    const int* dst = ei + N_EDGES;

    // preprocessing: merged cvt + bucket histogram, then scan -> scatter -> build
    hipMemsetAsync(bcnt, 0, 512 * 4, stream);
    k_prep<<<PREP_WL + PREP_WR + PREP_PJ + PREP_X + PREP_BC, 256, 0, stream>>>(
        WlAll, Wlh, Wll, WrAll, Wrh, Wrl, projW, pWh, pWl, x, xf, dst, bcnt);
    k_bscan<<<1, 512, 0, stream>>>(bcnt, bbase, bcur, offs);
    k_bucket<<<NBKT, 256, 0, stream>>>(src, dst, bcur, pairs);
    k_build<<<NBKT, 256, 0, stream>>>(pairs, bbase, offs, invd, csr_src);

    int gl = (N_NODES + 127) / 128;      // 782 blocks of 512 threads (128 rows each)
    int ga = N_NODES / 2 / 4;            // 12500 blocks (2 nodes per wave, 4 waves/block)

    // layer 0: hin = xf (fp16); skip = x@projW^T+projB fused; writes h0f
    k_agg_f16<<<ga, 256, 0, stream>>>(xf, offs, csr_src, invd, aggh);
    k_layer<0><<<gl, 512, 0, stream>>>(aggh, xf,
                                       Wlh, Wll, Wrh, Wrl, pWh, pWl, projB,
                                       lbAll, gAll, btAll, h0f,
                                       nullptr, nullptr, nullptr, nullptr, nullptr);
    // layer 1: hin = skip = h0f (fp16); writes h1f
    k_agg_f16<<<ga, 256, 0, stream>>>(h0f, offs, csr_src, invd, aggh);
    k_layer<1><<<gl, 512, 0, stream>>>(aggh, h0f,
                                       Wlh + D * D, Wll + D * D, Wrh + D * D, Wrl + D * D,
                                       nullptr, nullptr, nullptr,
                                       lbAll + D, gAll + D, btAll + D, h1f,
                                       nullptr, nullptr, nullptr, nullptr, nullptr);
    // layer 2: hin = skip = h1f (fp16); fused head -> out
    k_agg_f16<<<ga, 256, 0, stream>>>(h1f, offs, csr_src, invd, aggh);
    k_layer<2><<<gl, 512, 0, stream>>>(aggh, h1f,
                                       Wlh + 2 * D * D, Wll + 2 * D * D,
                                       Wrh + 2 * D * D, Wrl + 2 * D * D,
                                       nullptr, nullptr, nullptr,
                                       lbAll + 2 * D, gAll + 2 * D, btAll + 2 * D,
                                       nullptr,
                                       hw, hbias, rr, alpha, out);
}

// Round 14
// 482.152 us; speedup vs baseline: 1.4240x; 1.0376x over previous
//
#include <hip/hip_runtime.h>
#include <math.h>

#define N_NODES 100000
#define N_EDGES 1600000
#define D 128
#define NBKT 391   // ceil(N_NODES/256) buckets of 256 dst nodes

// k_prep grid partition
#define PREP_WL 48     // 3*D*D/4 / 256
#define PREP_WR 48
#define PREP_PJ 16     // D*D/4 / 256
#define PREP_X  12500  // N_NODES*D/4 / 256
#define PREP_BC 391    // edge-count blocks (4096 edges each)

typedef __attribute__((ext_vector_type(8))) _Float16 half8;
typedef __attribute__((ext_vector_type(4))) float floatx4;

__device__ __forceinline__ unsigned short f2h(float f) {
    union { _Float16 h; unsigned short u; } c;
    c.h = (_Float16)f;
    return c.u;
}
__device__ __forceinline__ float h2f(unsigned short u) {
    union { unsigned short u; _Float16 h; } c;
    c.u = u;
    return (float)c.h;
}

// ---- async stage ONE 32KB weight array into an LDS buffer (512 threads) ----
// entry e = (ct*4+ks)*64 + lane  holds  W[ct*16+(lane&15)][ks*32+(lane>>4)*8 .. +8]
typedef __attribute__((address_space(3))) unsigned short lds_us;
typedef __attribute__((address_space(1))) const unsigned short gl_us;

__device__ __forceinline__ void stageG(unsigned short* sWbuf,
                                       const unsigned short* __restrict__ W, int tid) {
#pragma unroll
    for (int i = 0; i < 4; ++i) {
        int e = tid + 512 * i;
        int ct = e >> 8;
        int ks = (e >> 6) & 3;
        int q = (e >> 4) & 3;
        int l = e & 15;
        const unsigned short* g = W + (size_t)(ct * 16 + l) * D + ks * 32 + q * 8;
        unsigned short* lp = sWbuf + (size_t)(i * 512 + (tid & ~63)) * 8;
        __builtin_amdgcn_global_load_lds((gl_us*)g, (lds_us*)lp, 16, 0, 0);
    }
}

// one full pass over a staged 32KB fp16 weight array: 4ks x 8ct fragments, f16 MFMA.
// sched_barrier(0) between ks groups bounds the ds_read prefetch window to 8 wf
// fragments (32 VGPR) — r13's unbounded window hit 128 VGPR + ~29MB/dispatch spills.
__device__ __forceinline__ void computeP16(const unsigned short* sWbuf, int lane,
                                           const half8* A, floatx4* acc) {
#pragma unroll
    for (int ks = 0; ks < 4; ++ks) {
#pragma unroll
        for (int ct = 0; ct < 8; ++ct) {
            half8 wf = *(const half8*)(sWbuf + ((ct * 4 + ks) * 64 + lane) * 8);
            acc[ct] = __builtin_amdgcn_mfma_f32_16x16x32_f16(A[ks], wf, acc[ct], 0, 0, 0);
        }
        __builtin_amdgcn_sched_barrier(0);
    }
}

// ---------------- merged preprocessing: fp16 weight splits + x->fp16 + bucket hist ----
// W = W_h (fp16 RNE) + W_l (fp16 of residual): ~20+ bit effective weight precision
__device__ __forceinline__ void cvt_split_body(const float* __restrict__ s,
                                               unsigned short* __restrict__ hi,
                                               unsigned short* __restrict__ lo,
                                               int lb, int n4, int tid) {
    int i = lb * 256 + tid;
    if (i < n4) {
        float4 v = ((const float4*)s)[i];
        float f[4] = {v.x, v.y, v.z, v.w};
        ushort4 h, l;
        unsigned short* hp = (unsigned short*)&h;
        unsigned short* lp = (unsigned short*)&l;
#pragma unroll
        for (int c = 0; c < 4; ++c) {
            unsigned short hh = f2h(f[c]);
            hp[c] = hh;
            lp[c] = f2h(f[c] - h2f(hh));
        }
        ((ushort4*)hi)[i] = h;
        ((ushort4*)lo)[i] = l;
    }
}

__global__ __launch_bounds__(256) void k_prep(
    const float* __restrict__ WlAll, unsigned short* __restrict__ Wlh, unsigned short* __restrict__ Wll,
    const float* __restrict__ WrAll, unsigned short* __restrict__ Wrh, unsigned short* __restrict__ Wrl,
    const float* __restrict__ projW, unsigned short* __restrict__ pWh, unsigned short* __restrict__ pWl,
    const float* __restrict__ x, unsigned short* __restrict__ xf,
    const int* __restrict__ dst, int* __restrict__ bcnt) {
    __shared__ int h[NBKT];
    int tid = threadIdx.x;
    int b = blockIdx.x;
    if (b < PREP_WL) { cvt_split_body(WlAll, Wlh, Wll, b, 3 * D * D / 4, tid); return; }
    b -= PREP_WL;
    if (b < PREP_WR) { cvt_split_body(WrAll, Wrh, Wrl, b, 3 * D * D / 4, tid); return; }
    b -= PREP_WR;
    if (b < PREP_PJ) { cvt_split_body(projW, pWh, pWl, b, D * D / 4, tid); return; }
    b -= PREP_PJ;
    if (b < PREP_X) {
        int i = b * 256 + tid;
        if (i < N_NODES * D / 4) {
            float4 v = ((const float4*)x)[i];
            ushort4 o;
            o.x = f2h(v.x); o.y = f2h(v.y); o.z = f2h(v.z); o.w = f2h(v.w);
            ((ushort4*)xf)[i] = o;
        }
        return;
    }
    b -= PREP_X;
    // bucket histogram section: 4096 edges per block, LDS-reduced
    for (int i = tid; i < NBKT; i += 256) h[i] = 0;
    __syncthreads();
    int e0 = b * 4096;
#pragma unroll
    for (int i = 0; i < 16; ++i) {
        int e = e0 + tid + i * 256;
        if (e < N_EDGES) atomicAdd(&h[dst[e] >> 8], 1);
    }
    __syncthreads();
    for (int i = tid; i < NBKT; i += 256) {
        int c = h[i];
        if (c) atomicAdd(&bcnt[i], c);
    }
}

// ---------------- bucket scan: 391 counts -> bases + cursors (1 block) ----------------
__global__ void k_bscan(const int* __restrict__ bcnt, int* __restrict__ bbase,
                        int* __restrict__ bcur, int* __restrict__ offs) {
    __shared__ int tmp[512];
    int tid = threadIdx.x;
    int v = (tid < NBKT) ? bcnt[tid] : 0;
    tmp[tid] = v;
    __syncthreads();
    for (int off = 1; off < 512; off <<= 1) {
        int t = (tid >= off) ? tmp[tid - off] : 0;
        __syncthreads();
        if (tid >= off) tmp[tid] += t;
        __syncthreads();
    }
    int ex = tmp[tid] - v;   // exclusive prefix
    if (tid < NBKT) {
        bbase[tid] = ex;
        bcur[tid] = ex;
    }
    if (tid == 0) {
        bbase[NBKT] = N_EDGES;
        offs[N_NODES] = N_EDGES;
    }
}

// pass A: scatter (src,dst) pairs bucket-contiguous (dst>>8 buckets)
__global__ __launch_bounds__(256) void k_bucket(const int* __restrict__ src,
                                                const int* __restrict__ dst,
                                                int* __restrict__ bcur, uint2* __restrict__ pairs) {
    __shared__ int cnt[NBKT];
    __shared__ int off[NBKT];
    int tid = threadIdx.x;
    for (int i = tid; i < NBKT; i += 256) cnt[i] = 0;
    __syncthreads();
    int e0 = blockIdx.x * 4096;
    int mydst[16], mysrc[16];
#pragma unroll
    for (int i = 0; i < 16; ++i) {
        int e = e0 + tid + i * 256;
        int d = (e < N_EDGES) ? dst[e] : -1;
        mydst[i] = d;
        mysrc[i] = (e < N_EDGES) ? src[e] : 0;
        if (d >= 0) atomicAdd(&cnt[d >> 8], 1);
    }
    __syncthreads();
    for (int b = tid; b < NBKT; b += 256) {
        int c = cnt[b];
        off[b] = c ? atomicAdd(&bcur[b], c) : 0;
    }
    __syncthreads();
#pragma unroll
    for (int i = 0; i < 16; ++i) {
        int d = mydst[i];
        if (d >= 0) {
            int p = atomicAdd(&off[d >> 8], 1);
            pairs[p] = make_uint2((unsigned)mysrc[i], (unsigned)d);
        }
    }
}

// pass B: per bucket — LDS count + scan -> offs/invd/csr, all cursors in LDS
__global__ __launch_bounds__(256) void k_build(const uint2* __restrict__ pairs,
                                               const int* __restrict__ bbase,
                                               int* __restrict__ offs, float* __restrict__ invd,
                                               int* __restrict__ csr_src) {
    __shared__ int cnt[256];
    __shared__ int scn[256];
    __shared__ int cur[256];
    int b = blockIdx.x, tid = threadIdx.x;
    int node0 = b << 8;
    int nn = N_NODES - node0; if (nn > 256) nn = 256;
    int beg = bbase[b], end = bbase[b + 1];

    cnt[tid] = 0;
    __syncthreads();
    for (int e = beg + tid; e < end; e += 256) atomicAdd(&cnt[pairs[e].y & 255u], 1);
    __syncthreads();
    int v = cnt[tid];
    scn[tid] = v;
    __syncthreads();
    for (int off = 1; off < 256; off <<= 1) {
        int t = (tid >= off) ? scn[tid - off] : 0;
        __syncthreads();
        if (tid >= off) scn[tid] += t;
        __syncthreads();
    }
    int start = beg + scn[tid] - v;   // global start of this node's edge range
    if (tid < nn) {
        offs[node0 + tid] = start;
        invd[node0 + tid] = 1.0f / (float)(v > 1 ? v : 1);
    }
    cur[tid] = start;
    __syncthreads();
    for (int e = beg + tid; e < end; e += 256) {
        uint2 pr = pairs[e];
        int p = atomicAdd(&cur[pr.y & 255u], 1);
        csr_src[p] = (int)pr.x;
    }
}

// ---------------- mean aggregation: dual-node waves, fp16 gather -> fp16 agg --------
// sums in fp32, stores the mean rounded to fp16
__global__ void k_agg_f16(const unsigned short* __restrict__ hf, const int* __restrict__ offs,
                          const int* __restrict__ csr_src, const float* __restrict__ inv_deg,
                          unsigned short* __restrict__ aggh) {
    int gw = (blockIdx.x * 256 + threadIdx.x) >> 6;   // global wave id
    int lane = threadIdx.x & 63;
    int half = lane >> 5, l32 = lane & 31;
    int node = gw * 2 + half;
    int beg = offs[node], end = offs[node + 1];
    float a0 = 0.f, a1 = 0.f, a2 = 0.f, a3 = 0.f;
    int e = beg;
    for (; e + 7 < end; e += 8) {
        int ss[8];
#pragma unroll
        for (int i = 0; i < 8; ++i) ss[i] = csr_src[e + i];
        uint2 vv[8];
#pragma unroll
        for (int i = 0; i < 8; ++i)
            vv[i] = ((const uint2*)(hf + (size_t)ss[i] * D))[l32];
#pragma unroll
        for (int i = 0; i < 8; ++i) {
            a0 += h2f((unsigned short)(vv[i].x & 0xffffu));
            a1 += h2f((unsigned short)(vv[i].x >> 16));
            a2 += h2f((unsigned short)(vv[i].y & 0xffffu));
            a3 += h2f((unsigned short)(vv[i].y >> 16));
        }
    }
    for (; e + 3 < end; e += 4) {
        int ss[4];
#pragma unroll
        for (int i = 0; i < 4; ++i) ss[i] = csr_src[e + i];
        uint2 vv[4];
#pragma unroll
        for (int i = 0; i < 4; ++i)
            vv[i] = ((const uint2*)(hf + (size_t)ss[i] * D))[l32];
#pragma unroll
        for (int i = 0; i < 4; ++i) {
            a0 += h2f((unsigned short)(vv[i].x & 0xffffu));
            a1 += h2f((unsigned short)(vv[i].x >> 16));
            a2 += h2f((unsigned short)(vv[i].y & 0xffffu));
            a3 += h2f((unsigned short)(vv[i].y >> 16));
        }
    }
    for (; e < end; ++e) {
        int s = csr_src[e];
        uint2 v = ((const uint2*)(hf + (size_t)s * D))[l32];
        a0 += h2f((unsigned short)(v.x & 0xffffu));
        a1 += h2f((unsigned short)(v.x >> 16));
        a2 += h2f((unsigned short)(v.y & 0xffffu));
        a3 += h2f((unsigned short)(v.y >> 16));
    }
    float id = inv_deg[node];
    ushort4 o;
    o.x = f2h(a0 * id); o.y = f2h(a1 * id); o.z = f2h(a2 * id); o.w = f2h(a3 * id);
    ((ushort4*)(aggh + (size_t)node * D))[l32] = o;
}

// ---------------- fused SAGE layer v14: native f16 MFMA, bounded prefetch window -----
// MODE 0: hin = xf (fp16); skip = x@projW^T+projB fused (2 proj passes); writes houtf
// MODE 1: hin = skip = hinh (fp16); writes houtf
// MODE 2: hin = skip = hinh (fp16); fused head -> outp
template <int MODE>
__global__ __launch_bounds__(512) void k_layer(
    const unsigned short* __restrict__ aggh,   // fp16 agg
    const unsigned short* __restrict__ hinh,   // fp16 h (or xf in MODE 0)
    const unsigned short* __restrict__ Wlh, const unsigned short* __restrict__ Wll,
    const unsigned short* __restrict__ Wrh, const unsigned short* __restrict__ Wrl,
    const unsigned short* __restrict__ pWh, const unsigned short* __restrict__ pWl,
    const float* __restrict__ projB,
    const float* __restrict__ lb, const float* __restrict__ g,
    const float* __restrict__ beta,
    unsigned short* __restrict__ houtf,
    const float* __restrict__ hw, const float* __restrict__ hb_bias,
    const float* __restrict__ rr, const float* __restrict__ alphap,
    float* __restrict__ outp) {
    __shared__ unsigned short sW[2][16384];   // 2 x 32KB double buffer

    int tid = threadIdx.x;
    int w = tid >> 6, lane = tid & 63;
    int quad = lane >> 4, l16 = lane & 15;
    int base = blockIdx.x * 128 + w * 16;

    int ar = base + l16; if (ar > N_NODES - 1) ar = N_NODES - 1;
    int koff = quad * 8;

    floatx4 z = {0.f, 0.f, 0.f, 0.f};
    floatx4 acc[8];
#pragma unroll
    for (int ct = 0; ct < 8; ++ct) acc[ct] = z;

    // prologue: async-stage Wl_h into buf0; load A-frags (direct fp16) under in-flight loads
    stageG(sW[0], Wlh, tid);
    half8 ah[4];
#pragma unroll
    for (int ks = 0; ks < 4; ++ks)
        ah[ks] = *(const half8*)(aggh + (size_t)ar * D + ks * 32 + koff);
    __syncthreads();

    // phase 1: stage Wl_l | compute A*Wl_h
    stageG(sW[1], Wll, tid);
    computeP16(sW[0], lane, ah, acc);
    __syncthreads();

    // phase 2: stage Wr_h; load B-frags | compute A*Wl_l
    stageG(sW[0], Wrh, tid);
    half8 bh[4];
#pragma unroll
    for (int ks = 0; ks < 4; ++ks)
        bh[ks] = *(const half8*)(hinh + (size_t)ar * D + ks * 32 + koff);
    computeP16(sW[1], lane, ah, acc);
    __syncthreads();

    // phase 3: stage Wr_l | compute B*Wr_h
    stageG(sW[1], Wrl, tid);
    computeP16(sW[0], lane, bh, acc);
    __syncthreads();

    // phase 4: (MODE0: stage proj_h) | compute B*Wr_l
    if (MODE == 0) stageG(sW[0], pWh, tid);
    computeP16(sW[1], lane, bh, acc);

    floatx4 accR[8];
    if (MODE == 0) {
#pragma unroll
        for (int ct = 0; ct < 8; ++ct) accR[ct] = z;
        __syncthreads();
        // phase 5: stage proj_l | compute B*proj_h
        stageG(sW[1], pWl, tid);
        computeP16(sW[0], lane, bh, accR);
        __syncthreads();
        // phase 6: compute B*proj_l
        computeP16(sW[1], lane, bh, accR);
    }

    // bias + relu in-register
    float lbv[8], gv[8], bv[8];
#pragma unroll
    for (int ct = 0; ct < 8; ++ct) {
        int n = ct * 16 + l16;
        lbv[ct] = lb[n];
        gv[ct] = g[n];
        bv[ct] = beta[n];
    }
#pragma unroll
    for (int ct = 0; ct < 8; ++ct)
#pragma unroll
        for (int r = 0; r < 4; ++r)
            acc[ct][r] = fmaxf(acc[ct][r] + lbv[ct], 0.f);

    // LN stats per row (row = quad*4+r), in-register
    float mu[4], rs[4];
#pragma unroll
    for (int r = 0; r < 4; ++r) {
        float s = 0.f, ss = 0.f;
#pragma unroll
        for (int ct = 0; ct < 8; ++ct) {
            float v = acc[ct][r];
            s += v;
            ss += v * v;
        }
#pragma unroll
        for (int m = 1; m < 16; m <<= 1) {
            s += __shfl_xor(s, m, 64);
            ss += __shfl_xor(ss, m, 64);
        }
        float m_ = s * (1.0f / 128.0f);
        float v_ = ss * (1.0f / 128.0f) - m_ * m_;
        mu[r] = m_;
        rs[r] = rsqrtf(v_ + 1e-5f);
    }

    float pbv[8], hwv[8];
    if (MODE == 0) {
#pragma unroll
        for (int ct = 0; ct < 8; ++ct) pbv[ct] = projB[ct * 16 + l16];
    }
    if (MODE == 2) {
#pragma unroll
        for (int ct = 0; ct < 8; ++ct) hwv[ct] = hw[ct * 16 + l16];
    }

    // epilogue — skip from fp16 h (modes 1/2) or fused proj (mode 0); fp16-only h out
#pragma unroll
    for (int r = 0; r < 4; ++r) {
        int crow = base + quad * 4 + r;
        bool valid = (crow < N_NODES);
        float m_ = mu[r], rs_ = rs[r];
        size_t ro = (size_t)crow * D;
        if (MODE == 2) {
            float s = 0.f;
#pragma unroll
            for (int ct = 0; ct < 8; ++ct) {
                int col = ct * 16 + l16;
                float sk = valid ? h2f(hinh[ro + col]) : 0.f;
                float o = (acc[ct][r] - m_) * rs_ * gv[ct] + bv[ct] + sk;
                s += o * hwv[ct];
            }
#pragma unroll
            for (int m = 1; m < 16; m <<= 1) s += __shfl_xor(s, m, 64);
            if (l16 == 0 && valid) {
                float a = 1.0f / (1.0f + expf(-alphap[0]));
                outp[crow] = a * rr[crow] + (1.0f - a) * (s + hb_bias[0]);
            }
        } else {
            if (!valid) continue;
#pragma unroll
            for (int ct = 0; ct < 8; ++ct) {
                int col = ct * 16 + l16;
                float sk = (MODE == 0) ? (accR[ct][r] + pbv[ct]) : h2f(hinh[ro + col]);
                float o = (acc[ct][r] - m_) * rs_ * gv[ct] + bv[ct] + sk;
                houtf[ro + col] = f2h(o);
            }
        }
    }
}

// ---------------- launch ----------------
extern "C" void kernel_launch(void* const* d_in, const int* in_sizes, int n_in,
                              void* d_out, int out_size, void* d_ws, size_t ws_size,
                              hipStream_t stream) {
    const float* x     = (const float*)d_in[0];
    const int*   ei    = (const int*)d_in[1];
    const float* rr    = (const float*)d_in[2];
    const float* projW = (const float*)d_in[3];
    const float* projB = (const float*)d_in[4];
    const float* WlAll = (const float*)d_in[5];
    const float* lbAll = (const float*)d_in[6];
    const float* WrAll = (const float*)d_in[7];
    const float* gAll  = (const float*)d_in[8];
    const float* btAll = (const float*)d_in[9];
    const float* hw    = (const float*)d_in[10];
    const float* hbias = (const float*)d_in[11];
    const float* alpha = (const float*)d_in[12];
    float* out = (float*)d_out;

    char* p = (char*)d_ws;
    unsigned short* aggh = (unsigned short*)p; p += (size_t)N_NODES * D * 2;
    unsigned short* xf   = (unsigned short*)p; p += (size_t)N_NODES * D * 2;
    unsigned short* h0f  = (unsigned short*)p; p += (size_t)N_NODES * D * 2;
    unsigned short* h1f  = (unsigned short*)p; p += (size_t)N_NODES * D * 2;
    uint2* pairs = (uint2*)p; p += (size_t)N_EDGES * 8;
    unsigned short* Wlh = (unsigned short*)p; p += (size_t)3 * D * D * 2;
    unsigned short* Wll = (unsigned short*)p; p += (size_t)3 * D * D * 2;
    unsigned short* Wrh = (unsigned short*)p; p += (size_t)3 * D * D * 2;
    unsigned short* Wrl = (unsigned short*)p; p += (size_t)3 * D * D * 2;
    unsigned short* pWh = (unsigned short*)p; p += (size_t)D * D * 2;
    unsigned short* pWl = (unsigned short*)p; p += (size_t)D * D * 2;
    float* invd  = (float*)p; p += (size_t)N_NODES * 4;
    int* offs    = (int*)p; p += (size_t)(N_NODES + 2) * 4;
    int* csr_src = (int*)p; p += (size_t)N_EDGES * 4;
    int* bcnt    = (int*)p; p += 512 * 4;
    int* bbase   = (int*)p; p += 512 * 4;
    int* bcur    = (int*)p; p += 512 * 4;

    const int* src = ei;
    const int* dst = ei + N_EDGES;

    // preprocessing: merged cvt + bucket histogram, then scan -> scatter -> build
    hipMemsetAsync(bcnt, 0, 512 * 4, stream);
    k_prep<<<PREP_WL + PREP_WR + PREP_PJ + PREP_X + PREP_BC, 256, 0, stream>>>(
        WlAll, Wlh, Wll, WrAll, Wrh, Wrl, projW, pWh, pWl, x, xf, dst, bcnt);
    k_bscan<<<1, 512, 0, stream>>>(bcnt, bbase, bcur, offs);
    k_bucket<<<NBKT, 256, 0, stream>>>(src, dst, bcur, pairs);
    k_build<<<NBKT, 256, 0, stream>>>(pairs, bbase, offs, invd, csr_src);

    int gl = (N_NODES + 127) / 128;      // 782 blocks of 512 threads (128 rows each)
    int ga = N_NODES / 2 / 4;            // 12500 blocks (2 nodes per wave, 4 waves/block)

    // layer 0: hin = xf (fp16); skip = x@projW^T+projB fused; writes h0f
    k_agg_f16<<<ga, 256, 0, stream>>>(xf, offs, csr_src, invd, aggh);
    k_layer<0><<<gl, 512, 0, stream>>>(aggh, xf,
                                       Wlh, Wll, Wrh, Wrl, pWh, pWl, projB,
                                       lbAll, gAll, btAll, h0f,
                                       nullptr, nullptr, nullptr, nullptr, nullptr);
    // layer 1: hin = skip = h0f (fp16); writes h1f
    k_agg_f16<<<ga, 256, 0, stream>>>(h0f, offs, csr_src, invd, aggh);
    k_layer<1><<<gl, 512, 0, stream>>>(aggh, h0f,
                                       Wlh + D * D, Wll + D * D, Wrh + D * D, Wrl + D * D,
                                       nullptr, nullptr, nullptr,
                                       lbAll + D, gAll + D, btAll + D, h1f,
                                       nullptr, nullptr, nullptr, nullptr, nullptr);
    // layer 2: hin = skip = h1f (fp16); fused head -> out
    k_agg_f16<<<ga, 256, 0, stream>>>(h1f, offs, csr_src, invd, aggh);
    k_layer<2><<<gl, 512, 0, stream>>>(aggh, h1f,
                                       Wlh + 2 * D * D, Wll + 2 * D * D,
                                       Wrh + 2 * D * D, Wrl + 2 * D * D,
                                       nullptr, nullptr, nullptr,
                                       lbAll + 2 * D, gAll + 2 * D, btAll + 2 * D,
                                       nullptr,
                                       hw, hbias, rr, alpha, out);
}

// Round 15
// 480.191 us; speedup vs baseline: 1.4298x; 1.0041x over previous
//
#include <hip/hip_runtime.h>
#include <math.h>

#define N_NODES 100000
#define N_EDGES 1600000
#define D 128
#define NBKT 391   // ceil(N_NODES/256) buckets of 256 dst nodes

// k_prep grid partition
#define PREP_WL 48     // 3*D*D/4 / 256
#define PREP_WR 48
#define PREP_PJ 16     // D*D/4 / 256
#define PREP_X  12500  // N_NODES*D/4 / 256
#define PREP_BC 391    // edge-count blocks (4096 edges each)

typedef __attribute__((ext_vector_type(8))) _Float16 half8;
typedef __attribute__((ext_vector_type(4))) float floatx4;

__device__ __forceinline__ unsigned short f2h(float f) {
    union { _Float16 h; unsigned short u; } c;
    c.h = (_Float16)f;
    return c.u;
}
__device__ __forceinline__ float h2f(unsigned short u) {
    union { unsigned short u; _Float16 h; } c;
    c.u = u;
    return (float)c.h;
}

// ---- async stage ONE 32KB weight array into an LDS buffer (512 threads) ----
// entry e = (ct*4+ks)*64 + lane  holds  W[ct*16+(lane&15)][ks*32+(lane>>4)*8 .. +8]
typedef __attribute__((address_space(3))) unsigned short lds_us;
typedef __attribute__((address_space(1))) const unsigned short gl_us;

__device__ __forceinline__ void stageG(unsigned short* sWbuf,
                                       const unsigned short* __restrict__ W, int tid) {
#pragma unroll
    for (int i = 0; i < 4; ++i) {
        int e = tid + 512 * i;
        int ct = e >> 8;
        int ks = (e >> 6) & 3;
        int q = (e >> 4) & 3;
        int l = e & 15;
        const unsigned short* g = W + (size_t)(ct * 16 + l) * D + ks * 32 + q * 8;
        unsigned short* lp = sWbuf + (size_t)(i * 512 + (tid & ~63)) * 8;
        __builtin_amdgcn_global_load_lds((gl_us*)g, (lds_us*)lp, 16, 0, 0);
    }
}

// one full pass over a staged 32KB fp16 weight array: 4ks x 8ct fragments, f16 MFMA.
// sched_barrier(0) between ks groups bounds the ds_read prefetch window to 8 wf
// fragments (32 VGPR) — unbounded window hit 128 VGPR + ~29MB/dispatch spills (r13).
__device__ __forceinline__ void computeP16(const unsigned short* sWbuf, int lane,
                                           const half8* A, floatx4* acc) {
#pragma unroll
    for (int ks = 0; ks < 4; ++ks) {
#pragma unroll
        for (int ct = 0; ct < 8; ++ct) {
            half8 wf = *(const half8*)(sWbuf + ((ct * 4 + ks) * 64 + lane) * 8);
            acc[ct] = __builtin_amdgcn_mfma_f32_16x16x32_f16(A[ks], wf, acc[ct], 0, 0, 0);
        }
        __builtin_amdgcn_sched_barrier(0);
    }
}

// ---------------- merged preprocessing: fp16 weight splits + x->fp16 + bucket hist ----
// W = W_h (fp16 RNE) + W_l (fp16 of residual): ~20+ bit effective weight precision
__device__ __forceinline__ void cvt_split_body(const float* __restrict__ s,
                                               unsigned short* __restrict__ hi,
                                               unsigned short* __restrict__ lo,
                                               int lb, int n4, int tid) {
    int i = lb * 256 + tid;
    if (i < n4) {
        float4 v = ((const float4*)s)[i];
        float f[4] = {v.x, v.y, v.z, v.w};
        ushort4 h, l;
        unsigned short* hp = (unsigned short*)&h;
        unsigned short* lp = (unsigned short*)&l;
#pragma unroll
        for (int c = 0; c < 4; ++c) {
            unsigned short hh = f2h(f[c]);
            hp[c] = hh;
            lp[c] = f2h(f[c] - h2f(hh));
        }
        ((ushort4*)hi)[i] = h;
        ((ushort4*)lo)[i] = l;
    }
}

__global__ __launch_bounds__(256) void k_prep(
    const float* __restrict__ WlAll, unsigned short* __restrict__ Wlh, unsigned short* __restrict__ Wll,
    const float* __restrict__ WrAll, unsigned short* __restrict__ Wrh, unsigned short* __restrict__ Wrl,
    const float* __restrict__ projW, unsigned short* __restrict__ pWh, unsigned short* __restrict__ pWl,
    const float* __restrict__ x, unsigned short* __restrict__ xf,
    const int* __restrict__ dst, int* __restrict__ bcnt) {
    __shared__ int h[NBKT];
    int tid = threadIdx.x;
    int b = blockIdx.x;
    if (b < PREP_WL) { cvt_split_body(WlAll, Wlh, Wll, b, 3 * D * D / 4, tid); return; }
    b -= PREP_WL;
    if (b < PREP_WR) { cvt_split_body(WrAll, Wrh, Wrl, b, 3 * D * D / 4, tid); return; }
    b -= PREP_WR;
    if (b < PREP_PJ) { cvt_split_body(projW, pWh, pWl, b, D * D / 4, tid); return; }
    b -= PREP_PJ;
    if (b < PREP_X) {
        int i = b * 256 + tid;
        if (i < N_NODES * D / 4) {
            float4 v = ((const float4*)x)[i];
            ushort4 o;
            o.x = f2h(v.x); o.y = f2h(v.y); o.z = f2h(v.z); o.w = f2h(v.w);
            ((ushort4*)xf)[i] = o;
        }
        return;
    }
    b -= PREP_X;
    // bucket histogram section: 4096 edges per block, LDS-reduced
    for (int i = tid; i < NBKT; i += 256) h[i] = 0;
    __syncthreads();
    int e0 = b * 4096;
#pragma unroll
    for (int i = 0; i < 16; ++i) {
        int e = e0 + tid + i * 256;
        if (e < N_EDGES) atomicAdd(&h[dst[e] >> 8], 1);
    }
    __syncthreads();
    for (int i = tid; i < NBKT; i += 256) {
        int c = h[i];
        if (c) atomicAdd(&bcnt[i], c);
    }
}

// pass A: scatter (src,dst) pairs bucket-contiguous (dst>>8 buckets)
// 512 threads (r12-verified body); local LDS scan of bcnt replaces k_bscan —
// cursor = ex[bkt] + atomicAdd(&bcur[bkt], c), bcur zero-initialized by the memset.
__global__ __launch_bounds__(512) void k_bucket(const int* __restrict__ src,
                                                const int* __restrict__ dst,
                                                const int* __restrict__ bcnt,
                                                int* __restrict__ bcur,
                                                uint2* __restrict__ pairs) {
    __shared__ int ex[512];
    __shared__ int cnt[NBKT];
    __shared__ int off[NBKT];
    int tid = threadIdx.x;

    // local exclusive scan of the 391-entry global histogram
    int v = (tid < NBKT) ? bcnt[tid] : 0;
    ex[tid] = v;
    __syncthreads();
    for (int o = 1; o < 512; o <<= 1) {
        int t = (tid >= o) ? ex[tid - o] : 0;
        __syncthreads();
        if (tid >= o) ex[tid] += t;
        __syncthreads();
    }
    int myex = ex[tid] - v;   // exclusive prefix for bucket tid
    __syncthreads();
    if (tid < NBKT) ex[tid] = myex;   // ex[] now holds exclusive prefixes
    for (int i = tid; i < NBKT; i += 512) cnt[i] = 0;
    __syncthreads();

    int e0 = blockIdx.x * 4096;
    int mydst[8], mysrc[8];
#pragma unroll
    for (int i = 0; i < 8; ++i) {
        int e = e0 + tid + i * 512;
        int d = (e < N_EDGES) ? dst[e] : -1;
        mydst[i] = d;
        mysrc[i] = (e < N_EDGES) ? src[e] : 0;
        if (d >= 0) atomicAdd(&cnt[d >> 8], 1);
    }
    __syncthreads();
    for (int b = tid; b < NBKT; b += 512) {
        int c = cnt[b];
        off[b] = c ? (ex[b] + atomicAdd(&bcur[b], c)) : 0;
    }
    __syncthreads();
#pragma unroll
    for (int i = 0; i < 8; ++i) {
        int d = mydst[i];
        if (d >= 0) {
            int p = atomicAdd(&off[d >> 8], 1);
            pairs[p] = make_uint2((unsigned)mysrc[i], (unsigned)d);
        }
    }
}

// pass B: per bucket — local scan of bcnt gives beg/end; LDS count+scan -> offs/invd/csr
__global__ __launch_bounds__(512) void k_build(const uint2* __restrict__ pairs,
                                               const int* __restrict__ bcnt,
                                               int* __restrict__ offs, float* __restrict__ invd,
                                               int* __restrict__ csr_src) {
    __shared__ int ex[512];
    __shared__ int cnt[256];
    __shared__ int scn[256];
    __shared__ int cur[256];
    int b = blockIdx.x, tid = threadIdx.x;

    // local exclusive scan of the 391-entry global histogram -> bucket bases
    int v0 = (tid < NBKT) ? bcnt[tid] : 0;
    ex[tid] = v0;
    __syncthreads();
    for (int o = 1; o < 512; o <<= 1) {
        int t = (tid >= o) ? ex[tid - o] : 0;
        __syncthreads();
        if (tid >= o) ex[tid] += t;
        __syncthreads();
    }
    __syncthreads();
    int beg = ex[b] - ((b < NBKT) ? bcnt[b] : 0) + ((b == 0) ? 0 : 0);
    // exclusive prefix of bucket b = inclusive[b] - bcnt[b]
    beg = ex[b] - bcnt[b];
    int end = ex[b];   // inclusive prefix of bucket b = exclusive prefix of b+1

    int node0 = b << 8;
    int nn = N_NODES - node0; if (nn > 256) nn = 256;

    for (int i = tid; i < 256; i += 512) cnt[i] = 0;
    __syncthreads();
    for (int e = beg + tid; e < end; e += 512) atomicAdd(&cnt[pairs[e].y & 255u], 1);
    __syncthreads();
    int v = (tid < 256) ? cnt[tid] : 0;
    if (tid < 256) scn[tid] = v;
    __syncthreads();
    for (int o = 1; o < 256; o <<= 1) {
        int t = (tid >= o && tid < 256) ? scn[tid - o] : 0;
        __syncthreads();
        if (tid >= o && tid < 256) scn[tid] += t;
        __syncthreads();
    }
    if (tid < 256) {
        int start = beg + scn[tid] - v;
        if (tid < nn) {
            offs[node0 + tid] = start;
            invd[node0 + tid] = 1.0f / (float)(v > 1 ? v : 1);
        }
        cur[tid] = start;
    }
    if (b == 0 && tid == 0) offs[N_NODES] = N_EDGES;
    __syncthreads();
    for (int e = beg + tid; e < end; e += 512) {
        uint2 pr = pairs[e];
        int p = atomicAdd(&cur[pr.y & 255u], 1);
        csr_src[p] = (int)pr.x;
    }
}

// ---------------- mean aggregation: dual-node waves, fp16 gather -> fp16 agg --------
// sums in fp32, stores the mean rounded to fp16
__global__ void k_agg_f16(const unsigned short* __restrict__ hf, const int* __restrict__ offs,
                          const int* __restrict__ csr_src, const float* __restrict__ inv_deg,
                          unsigned short* __restrict__ aggh) {
    int gw = (blockIdx.x * 256 + threadIdx.x) >> 6;   // global wave id
    int lane = threadIdx.x & 63;
    int half = lane >> 5, l32 = lane & 31;
    int node = gw * 2 + half;
    int beg = offs[node], end = offs[node + 1];
    float a0 = 0.f, a1 = 0.f, a2 = 0.f, a3 = 0.f;
    int e = beg;
    for (; e + 7 < end; e += 8) {
        int ss[8];
#pragma unroll
        for (int i = 0; i < 8; ++i) ss[i] = csr_src[e + i];
        uint2 vv[8];
#pragma unroll
        for (int i = 0; i < 8; ++i)
            vv[i] = ((const uint2*)(hf + (size_t)ss[i] * D))[l32];
#pragma unroll
        for (int i = 0; i < 8; ++i) {
            a0 += h2f((unsigned short)(vv[i].x & 0xffffu));
            a1 += h2f((unsigned short)(vv[i].x >> 16));
            a2 += h2f((unsigned short)(vv[i].y & 0xffffu));
            a3 += h2f((unsigned short)(vv[i].y >> 16));
        }
    }
    for (; e + 3 < end; e += 4) {
        int ss[4];
#pragma unroll
        for (int i = 0; i < 4; ++i) ss[i] = csr_src[e + i];
        uint2 vv[4];
#pragma unroll
        for (int i = 0; i < 4; ++i)
            vv[i] = ((const uint2*)(hf + (size_t)ss[i] * D))[l32];
#pragma unroll
        for (int i = 0; i < 4; ++i) {
            a0 += h2f((unsigned short)(vv[i].x & 0xffffu));
            a1 += h2f((unsigned short)(vv[i].x >> 16));
            a2 += h2f((unsigned short)(vv[i].y & 0xffffu));
            a3 += h2f((unsigned short)(vv[i].y >> 16));
        }
    }
    for (; e < end; ++e) {
        int s = csr_src[e];
        uint2 v = ((const uint2*)(hf + (size_t)s * D))[l32];
        a0 += h2f((unsigned short)(v.x & 0xffffu));
        a1 += h2f((unsigned short)(v.x >> 16));
        a2 += h2f((unsigned short)(v.y & 0xffffu));
        a3 += h2f((unsigned short)(v.y >> 16));
    }
    float id = inv_deg[node];
    ushort4 o;
    o.x = f2h(a0 * id); o.y = f2h(a1 * id); o.z = f2h(a2 * id); o.w = f2h(a3 * id);
    ((ushort4*)(aggh + (size_t)node * D))[l32] = o;
}

// ---------------- fused SAGE layer (r14-proven): native f16 MFMA, bounded prefetch ---
// MODE 0: hin = xf (fp16); skip = x@projW^T+projB fused (2 proj passes); writes houtf
// MODE 1: hin = skip = hinh (fp16); writes houtf
// MODE 2: hin = skip = hinh (fp16); fused head -> outp
template <int MODE>
__global__ __launch_bounds__(512) void k_layer(
    const unsigned short* __restrict__ aggh,   // fp16 agg
    const unsigned short* __restrict__ hinh,   // fp16 h (or xf in MODE 0)
    const unsigned short* __restrict__ Wlh, const unsigned short* __restrict__ Wll,
    const unsigned short* __restrict__ Wrh, const unsigned short* __restrict__ Wrl,
    const unsigned short* __restrict__ pWh, const unsigned short* __restrict__ pWl,
    const float* __restrict__ projB,
    const float* __restrict__ lb, const float* __restrict__ g,
    const float* __restrict__ beta,
    unsigned short* __restrict__ houtf,
    const float* __restrict__ hw, const float* __restrict__ hb_bias,
    const float* __restrict__ rr, const float* __restrict__ alphap,
    float* __restrict__ outp) {
    __shared__ unsigned short sW[2][16384];   // 2 x 32KB double buffer

    int tid = threadIdx.x;
    int w = tid >> 6, lane = tid & 63;
    int quad = lane >> 4, l16 = lane & 15;
    int base = blockIdx.x * 128 + w * 16;

    int ar = base + l16; if (ar > N_NODES - 1) ar = N_NODES - 1;
    int koff = quad * 8;

    floatx4 z = {0.f, 0.f, 0.f, 0.f};
    floatx4 acc[8];
#pragma unroll
    for (int ct = 0; ct < 8; ++ct) acc[ct] = z;

    // prologue: async-stage Wl_h into buf0; load A-frags (direct fp16) under in-flight loads
    stageG(sW[0], Wlh, tid);
    half8 ah[4];
#pragma unroll
    for (int ks = 0; ks < 4; ++ks)
        ah[ks] = *(const half8*)(aggh + (size_t)ar * D + ks * 32 + koff);
    __syncthreads();

    // phase 1: stage Wl_l | compute A*Wl_h
    stageG(sW[1], Wll, tid);
    computeP16(sW[0], lane, ah, acc);
    __syncthreads();

    // phase 2: stage Wr_h; load B-frags | compute A*Wl_l
    stageG(sW[0], Wrh, tid);
    half8 bh[4];
#pragma unroll
    for (int ks = 0; ks < 4; ++ks)
        bh[ks] = *(const half8*)(hinh + (size_t)ar * D + ks * 32 + koff);
    computeP16(sW[1], lane, ah, acc);
    __syncthreads();

    // phase 3: stage Wr_l | compute B*Wr_h
    stageG(sW[1], Wrl, tid);
    computeP16(sW[0], lane, bh, acc);
    __syncthreads();

    // phase 4: (MODE0: stage proj_h) | compute B*Wr_l
    if (MODE == 0) stageG(sW[0], pWh, tid);
    computeP16(sW[1], lane, bh, acc);

    floatx4 accR[8];
    if (MODE == 0) {
#pragma unroll
        for (int ct = 0; ct < 8; ++ct) accR[ct] = z;
        __syncthreads();
        // phase 5: stage proj_l | compute B*proj_h
        stageG(sW[1], pWl, tid);
        computeP16(sW[0], lane, bh, accR);
        __syncthreads();
        // phase 6: compute B*proj_l
        computeP16(sW[1], lane, bh, accR);
    }

    // bias + relu in-register
    float lbv[8], gv[8], bv[8];
#pragma unroll
    for (int ct = 0; ct < 8; ++ct) {
        int n = ct * 16 + l16;
        lbv[ct] = lb[n];
        gv[ct] = g[n];
        bv[ct] = beta[n];
    }
#pragma unroll
    for (int ct = 0; ct < 8; ++ct)
#pragma unroll
        for (int r = 0; r < 4; ++r)
            acc[ct][r] = fmaxf(acc[ct][r] + lbv[ct], 0.f);

    // LN stats per row (row = quad*4+r), in-register
    float mu[4], rs[4];
#pragma unroll
    for (int r = 0; r < 4; ++r) {
        float s = 0.f, ss = 0.f;
#pragma unroll
        for (int ct = 0; ct < 8; ++ct) {
            float v = acc[ct][r];
            s += v;
            ss += v * v;
        }
#pragma unroll
        for (int m = 1; m < 16; m <<= 1) {
            s += __shfl_xor(s, m, 64);
            ss += __shfl_xor(ss, m, 64);
        }
        float m_ = s * (1.0f / 128.0f);
        float v_ = ss * (1.0f / 128.0f) - m_ * m_;
        mu[r] = m_;
        rs[r] = rsqrtf(v_ + 1e-5f);
    }

    float pbv[8], hwv[8];
    if (MODE == 0) {
#pragma unroll
        for (int ct = 0; ct < 8; ++ct) pbv[ct] = projB[ct * 16 + l16];
    }
    if (MODE == 2) {
#pragma unroll
        for (int ct = 0; ct < 8; ++ct) hwv[ct] = hw[ct * 16 + l16];
    }

    // epilogue — skip from fp16 h (modes 1/2) or fused proj (mode 0); fp16-only h out
#pragma unroll
    for (int r = 0; r < 4; ++r) {
        int crow = base + quad * 4 + r;
        bool valid = (crow < N_NODES);
        float m_ = mu[r], rs_ = rs[r];
        size_t ro = (size_t)crow * D;
        if (MODE == 2) {
            float s = 0.f;
#pragma unroll
            for (int ct = 0; ct < 8; ++ct) {
                int col = ct * 16 + l16;
                float sk = valid ? h2f(hinh[ro + col]) : 0.f;
                float o = (acc[ct][r] - m_) * rs_ * gv[ct] + bv[ct] + sk;
                s += o * hwv[ct];
            }
#pragma unroll
            for (int m = 1; m < 16; m <<= 1) s += __shfl_xor(s, m, 64);
            if (l16 == 0 && valid) {
                float a = 1.0f / (1.0f + expf(-alphap[0]));
                outp[crow] = a * rr[crow] + (1.0f - a) * (s + hb_bias[0]);
            }
        } else {
            if (!valid) continue;
#pragma unroll
            for (int ct = 0; ct < 8; ++ct) {
                int col = ct * 16 + l16;
                float sk = (MODE == 0) ? (accR[ct][r] + pbv[ct]) : h2f(hinh[ro + col]);
                float o = (acc[ct][r] - m_) * rs_ * gv[ct] + bv[ct] + sk;
                houtf[ro + col] = f2h(o);
            }
        }
    }
}

// ---------------- launch ----------------
extern "C" void kernel_launch(void* const* d_in, const int* in_sizes, int n_in,
                              void* d_out, int out_size, void* d_ws, size_t ws_size,
                              hipStream_t stream) {
    const float* x     = (const float*)d_in[0];
    const int*   ei    = (const int*)d_in[1];
    const float* rr    = (const float*)d_in[2];
    const float* projW = (const float*)d_in[3];
    const float* projB = (const float*)d_in[4];
    const float* WlAll = (const float*)d_in[5];
    const float* lbAll = (const float*)d_in[6];
    const float* WrAll = (const float*)d_in[7];
    const float* gAll  = (const float*)d_in[8];
    const float* btAll = (const float*)d_in[9];
    const float* hw    = (const float*)d_in[10];
    const float* hbias = (const float*)d_in[11];
    const float* alpha = (const float*)d_in[12];
    float* out = (float*)d_out;

    char* p = (char*)d_ws;
    unsigned short* aggh = (unsigned short*)p; p += (size_t)N_NODES * D * 2;
    unsigned short* xf   = (unsigned short*)p; p += (size_t)N_NODES * D * 2;
    unsigned short* h0f  = (unsigned short*)p; p += (size_t)N_NODES * D * 2;
    unsigned short* h1f  = (unsigned short*)p; p += (size_t)N_NODES * D * 2;
    uint2* pairs = (uint2*)p; p += (size_t)N_EDGES * 8;
    unsigned short* Wlh = (unsigned short*)p; p += (size_t)3 * D * D * 2;
    unsigned short* Wll = (unsigned short*)p; p += (size_t)3 * D * D * 2;
    unsigned short* Wrh = (unsigned short*)p; p += (size_t)3 * D * D * 2;
    unsigned short* Wrl = (unsigned short*)p; p += (size_t)3 * D * D * 2;
    unsigned short* pWh = (unsigned short*)p; p += (size_t)D * D * 2;
    unsigned short* pWl = (unsigned short*)p; p += (size_t)D * D * 2;
    float* invd  = (float*)p; p += (size_t)N_NODES * 4;
    int* offs    = (int*)p; p += (size_t)(N_NODES + 2) * 4;
    int* csr_src = (int*)p; p += (size_t)N_EDGES * 4;
    int* bcnt    = (int*)p; p += 512 * 4;   // bcnt and bcur contiguous: one memset
    int* bcur    = (int*)p; p += 512 * 4;

    const int* src = ei;
    const int* dst = ei + N_EDGES;

    // preprocessing: memset(bcnt+bcur) -> merged cvt+hist -> scatter -> build
    hipMemsetAsync(bcnt, 0, 2 * 512 * 4, stream);
    k_prep<<<PREP_WL + PREP_WR + PREP_PJ + PREP_X + PREP_BC, 256, 0, stream>>>(
        WlAll, Wlh, Wll, WrAll, Wrh, Wrl, projW, pWh, pWl, x, xf, dst, bcnt);
    k_bucket<<<NBKT, 512, 0, stream>>>(src, dst, bcnt, bcur, pairs);
    k_build<<<NBKT, 512, 0, stream>>>(pairs, bcnt, offs, invd, csr_src);

    int gl = (N_NODES + 127) / 128;      // 782 blocks of 512 threads (128 rows each)
    int ga = N_NODES / 2 / 4;            // 12500 blocks (2 nodes per wave, 4 waves/block)

    // layer 0: hin = xf (fp16); skip = x@projW^T+projB fused; writes h0f
    k_agg_f16<<<ga, 256, 0, stream>>>(xf, offs, csr_src, invd, aggh);
    k_layer<0><<<gl, 512, 0, stream>>>(aggh, xf,
                                       Wlh, Wll, Wrh, Wrl, pWh, pWl, projB,
                                       lbAll, gAll, btAll, h0f,
                                       nullptr, nullptr, nullptr, nullptr, nullptr);
    // layer 1: hin = skip = h0f (fp16); writes h1f
    k_agg_f16<<<ga, 256, 0, stream>>>(h0f, offs, csr_src, invd, aggh);
    k_layer<1><<<gl, 512, 0, stream>>>(aggh, h0f,
                                       Wlh + D * D, Wll + D * D, Wrh + D * D, Wrl + D * D,
                                       nullptr, nullptr, nullptr,
                                       lbAll + D, gAll + D, btAll + D, h1f,
                                       nullptr, nullptr, nullptr, nullptr, nullptr);
    // layer 2: hin = skip = h1f (fp16); fused head -> out
    k_agg_f16<<<ga, 256, 0, stream>>>(h1f, offs, csr_src, invd, aggh);
    k_layer<2><<<gl, 512, 0, stream>>>(aggh, h1f,
                                       Wlh + 2 * D * D, Wll + 2 * D * D,
                                       Wrh + 2 * D * D, Wrl + 2 * D * D,
                                       nullptr, nullptr, nullptr,
                                       lbAll + 2 * D, gAll + 2 * D, btAll + 2 * D,
                                       nullptr,
                                       hw, hbias, rr, alpha, out);
}